// Round 2
// baseline (642.898 us; speedup 1.0000x reference)
//
#include <hip/hip_runtime.h>
#include <hip/hip_bf16.h>

#define N_ROWS 8192
#define F_DIM  256

typedef __bf16 bf16x8_t __attribute__((ext_vector_type(8)));
typedef float  f32x4_t  __attribute__((ext_vector_type(4)));

static __device__ __forceinline__ unsigned short f2bf(float x) {
    union { __hip_bfloat16 h; unsigned short u; } c;
    c.h = __float2bfloat16(x);   // RNE
    return c.u;
}
static __device__ __forceinline__ unsigned pk2(float lo, float hi) {
    return (unsigned)f2bf(lo) | ((unsigned)f2bf(hi) << 16);
}
// 8 fp32 -> bf16x8 fragment (compiler emits v_cvt_pk_bf16_f32 pairs)
static __device__ __forceinline__ bf16x8_t cvt8(f32x4_t lo, f32x4_t hi) {
    union { unsigned u[4]; bf16x8_t v; } r;
    r.u[0] = pk2(lo[0], lo[1]);
    r.u[1] = pk2(lo[2], lo[3]);
    r.u[2] = pk2(hi[0], hi[1]);
    r.u[3] = pk2(hi[2], hi[3]);
    return r.v;
}

// ---------------------------------------------------------------------------
// K0: W [256][256] fp32 -> bf16, swizzled Ws[kb][n][kc]  (kb=k>>5, kc=k&31)
// so GEMM B-fragment (lane: n=l&15, k=q*8+j) is one contiguous 16B load.
// ---------------------------------------------------------------------------
__global__ __launch_bounds__(256) void wconv_kernel(const float* __restrict__ W,
                                                    unsigned short* __restrict__ Ws) {
    const int kb = blockIdx.x;            // 8 blocks of 32 k-rows
    const int t  = threadIdx.x;
    __shared__ float wt[32][257];
    const int r = t >> 3, g = t & 7;
    const float* src = W + (kb * 32 + r) * F_DIM + g * 32;
#pragma unroll
    for (int i = 0; i < 8; ++i) {
        float4 v = *(const float4*)(src + i * 4);
        wt[r][g * 32 + i * 4 + 0] = v.x;
        wt[r][g * 32 + i * 4 + 1] = v.y;
        wt[r][g * 32 + i * 4 + 2] = v.z;
        wt[r][g * 32 + i * 4 + 3] = v.w;
    }
    __syncthreads();
    // thread t = output column n; write 32 bf16 (64 B) contiguous
    unsigned o[16];
#pragma unroll
    for (int k = 0; k < 32; k += 2) o[k >> 1] = pk2(wt[k][t], wt[k + 1][t]);
    uint4* dst = (uint4*)(Ws + kb * 8192 + t * 32);
#pragma unroll
    for (int i = 0; i < 4; ++i) dst[i] = make_uint4(o[4*i], o[4*i+1], o[4*i+2], o[4*i+3]);
}

// ---------------------------------------------------------------------------
// K1: per 32-row band: rowsum(A) -> d=rsqrt, dvec; X = d*H -> bf16 swizzled
// Xs[kb][n][kc].  Reads 1 MB of A per block (268 MB total, HBM-bound).
// A streamed with NT loads (zero reuse here; gemm1 re-reads from HBM anyway
// since A=256MB >= L3).
// ---------------------------------------------------------------------------
__global__ __launch_bounds__(1024) void prep_kernel(const float* __restrict__ A,
                                                    const float* __restrict__ H,
                                                    float* __restrict__ dvec,
                                                    unsigned short* __restrict__ Xs) {
    const int kb = blockIdx.x;            // 256 blocks, 32 rows each
    const int t  = threadIdx.x;
    __shared__ float psum[32][33];
    __shared__ float dl[32];
    __shared__ float ht[32][257];

    const int r = t >> 5, g = t & 31;     // 32 threads per row
    const float* arow = A + (size_t)(kb * 32 + r) * N_ROWS;
    float s0 = 0.f, s1 = 0.f, s2 = 0.f, s3 = 0.f;
#pragma unroll 8
    for (int i = 0; i < 64; ++i) {
        f32x4_t v = __builtin_nontemporal_load((f32x4_t*)(arow + (i * 32 + g) * 4));
        s0 += v.x; s1 += v.y; s2 += v.z; s3 += v.w;
    }
    psum[r][g] = (s0 + s1) + (s2 + s3);
    __syncthreads();
    if (t < 32) {
        float s = 0.f;
#pragma unroll
        for (int i = 0; i < 32; ++i) s += psum[t][i];
        float d = 1.0f / sqrtf(s);
        dl[t] = d;
        dvec[kb * 32 + t] = d;
    }
    __syncthreads();
    {   // load H band pre-scaled by d_row into LDS
        const int hr = t >> 5, hg = t & 31;
        const float* hsrc = H + (size_t)(kb * 32 + hr) * F_DIM + hg * 8;
        float4 v0 = ((const float4*)hsrc)[0];
        float4 v1 = ((const float4*)hsrc)[1];
        const float d = dl[hr];
        ht[hr][hg * 8 + 0] = v0.x * d;
        ht[hr][hg * 8 + 1] = v0.y * d;
        ht[hr][hg * 8 + 2] = v0.z * d;
        ht[hr][hg * 8 + 3] = v0.w * d;
        ht[hr][hg * 8 + 4] = v1.x * d;
        ht[hr][hg * 8 + 5] = v1.y * d;
        ht[hr][hg * 8 + 6] = v1.z * d;
        ht[hr][hg * 8 + 7] = v1.w * d;
    }
    __syncthreads();
    // transpose-read: thread -> (n = t>>2, quarter q = t&3), write 16 B
    const int n = t >> 2, q = t & 3;
    unsigned o[4];
#pragma unroll
    for (int i = 0; i < 4; ++i) {
        int k = q * 8 + i * 2;
        o[i] = pk2(ht[k][n], ht[k + 1][n]);
    }
    *(uint4*)(Xs + kb * 8192 + n * 32 + q * 8) = make_uint4(o[0], o[1], o[2], o[3]);
}

// ---------------------------------------------------------------------------
// GEMM: out[M=8192, 256] (+opt d-scale, +opt relu) = Amat(fp32, cast bf16) @ Bs
// Bs is the swizzled bf16 layout [k>>5][n][k&31].
// BM=32, BN=256, 2 x BK=32 per iter. 512 thr = 8 waves (wave w: cols w*32..+31).
// BARRIER-FREE: no LDS. Each wave loads its own A-fragments directly
// (rows m / m+16, 8 consecutive fp32 = 2x dwordx4) and converts in-register.
// The 8 waves redundantly read the same 8KB A-tile per iter -> served by L1;
// HBM traffic unchanged. Without __syncthreads there is no forced
// vmcnt(0) drain per iteration, so the 1-iter register prefetch actually
// pipelines (compiler emits counted vmcnt).
// ---------------------------------------------------------------------------
template <int KITERS, int ASTRIDE, bool DSCALE, bool RELU>
__global__ __launch_bounds__(512, 2) void gemm_kernel(const float* __restrict__ Amat,
                                                      const unsigned short* __restrict__ Bs,
                                                      const float* __restrict__ dvec,
                                                      float* __restrict__ out) {
    const int t   = threadIdx.x;
    const int blk = blockIdx.x;               // 32-row M tile
    const int w = t >> 6, l = t & 63;
    const int m = l & 15, q = l >> 4;

    // A frag: af0 = A[blk*32+m][i*64 + s*32 + q*8 + j], af1 = same row+16
    const float* a0 = Amat + (size_t)(blk * 32 + m) * ASTRIDE + q * 8;
    const float* a1 = a0 + (size_t)16 * ASTRIDE;

    const unsigned short* bptr = Bs + (w * 32 + m) * 32 + q * 8;
    // +nt*512 for next 16-col tile, +8192 per sub-step, +16384 per iter

    f32x4_t acc[2][2] = {};                   // [mtile][ntile]

    f32x4_t a_cur[2][2][2];                   // [sub][row-frag][half]
    uint4   b_cur[2][2];
#pragma unroll
    for (int s = 0; s < 2; ++s) {
        a_cur[s][0][0] = *(const f32x4_t*)(a0 + s * 32);
        a_cur[s][0][1] = *(const f32x4_t*)(a0 + s * 32 + 4);
        a_cur[s][1][0] = *(const f32x4_t*)(a1 + s * 32);
        a_cur[s][1][1] = *(const f32x4_t*)(a1 + s * 32 + 4);
        b_cur[s][0] = *(const uint4*)(bptr + s * 8192);
        b_cur[s][1] = *(const uint4*)(bptr + s * 8192 + 512);
    }

    for (int i = 0; i < KITERS; ++i) {
        f32x4_t a_nxt[2][2][2]; uint4 b_nxt[2][2];
        if (i + 1 < KITERS) {
            const float* ap0 = a0 + (i + 1) * 64;
            const float* ap1 = a1 + (i + 1) * 64;
            const unsigned short* bp = bptr + (size_t)(i + 1) * 16384;
#pragma unroll
            for (int s = 0; s < 2; ++s) {
                a_nxt[s][0][0] = *(const f32x4_t*)(ap0 + s * 32);
                a_nxt[s][0][1] = *(const f32x4_t*)(ap0 + s * 32 + 4);
                a_nxt[s][1][0] = *(const f32x4_t*)(ap1 + s * 32);
                a_nxt[s][1][1] = *(const f32x4_t*)(ap1 + s * 32 + 4);
                b_nxt[s][0] = *(const uint4*)(bp + s * 8192);
                b_nxt[s][1] = *(const uint4*)(bp + s * 8192 + 512);
            }
        }
#pragma unroll
        for (int s = 0; s < 2; ++s) {
            bf16x8_t af0 = cvt8(a_cur[s][0][0], a_cur[s][0][1]);
            bf16x8_t af1 = cvt8(a_cur[s][1][0], a_cur[s][1][1]);
            bf16x8_t bf0 = __builtin_bit_cast(bf16x8_t, b_cur[s][0]);
            bf16x8_t bf1 = __builtin_bit_cast(bf16x8_t, b_cur[s][1]);
            acc[0][0] = __builtin_amdgcn_mfma_f32_16x16x32_bf16(af0, bf0, acc[0][0], 0, 0, 0);
            acc[0][1] = __builtin_amdgcn_mfma_f32_16x16x32_bf16(af0, bf1, acc[0][1], 0, 0, 0);
            acc[1][0] = __builtin_amdgcn_mfma_f32_16x16x32_bf16(af1, bf0, acc[1][0], 0, 0, 0);
            acc[1][1] = __builtin_amdgcn_mfma_f32_16x16x32_bf16(af1, bf1, acc[1][1], 0, 0, 0);
        }
#pragma unroll
        for (int s = 0; s < 2; ++s) {
            a_cur[s][0][0] = a_nxt[s][0][0];
            a_cur[s][0][1] = a_nxt[s][0][1];
            a_cur[s][1][0] = a_nxt[s][1][0];
            a_cur[s][1][1] = a_nxt[s][1][1];
            b_cur[s][0] = b_nxt[s][0];
            b_cur[s][1] = b_nxt[s][1];
        }
    }

    // epilogue: C/D layout row=q*4+r, col=lane&15
    const int gcol0 = w * 32 + m;
#pragma unroll
    for (int mt = 0; mt < 2; ++mt) {
#pragma unroll
        for (int r = 0; r < 4; ++r) {
            const int grow = blk * 32 + mt * 16 + q * 4 + r;
            float ds = 1.0f;
            if (DSCALE) ds = dvec[grow];
#pragma unroll
            for (int nt = 0; nt < 2; ++nt) {
                float v = acc[mt][nt][r] * ds;
                if (RELU) v = fmaxf(v, 0.f);
                out[(size_t)grow * F_DIM + gcol0 + nt * 16] = v;
            }
        }
    }
}

// ---------------------------------------------------------------------------
extern "C" void kernel_launch(void* const* d_in, const int* in_sizes, int n_in,
                              void* d_out, int out_size, void* d_ws, size_t ws_size,
                              hipStream_t stream) {
    (void)in_sizes; (void)n_in; (void)out_size; (void)ws_size;
    const float* H = (const float*)d_in[0];
    const float* A = (const float*)d_in[1];
    const float* W = (const float*)d_in[2];
    float* out = (float*)d_out;

    char* ws = (char*)d_ws;
    float*          dvec = (float*)ws;                                   //  32 KB
    unsigned short* Xs   = (unsigned short*)(ws + (32 << 10));           //   4 MB
    unsigned short* Wsz  = (unsigned short*)(ws + (32 << 10) + (4 << 20)); // 128 KB
    float*          Y    = (float*)(ws + (32 << 10) + (4 << 20) + (128 << 10)); // 8 MB

    wconv_kernel<<<dim3(8),   dim3(256),  0, stream>>>(W, Wsz);
    prep_kernel <<<dim3(256), dim3(1024), 0, stream>>>(A, H, dvec, Xs);
    gemm_kernel<128, 8192, true,  false><<<dim3(256), dim3(512), 0, stream>>>(A, Xs, dvec, Y);
    gemm_kernel<4,   256,  false, true ><<<dim3(256), dim3(512), 0, stream>>>(Y, Wsz, nullptr, out);
}

// Round 3
// 457.011 us; speedup vs baseline: 1.4067x; 1.4067x over previous
//
#include <hip/hip_runtime.h>
#include <hip/hip_bf16.h>

#define N_ROWS 8192
#define F_DIM  256

typedef __bf16 bf16x8_t __attribute__((ext_vector_type(8)));
typedef float  f32x4_t  __attribute__((ext_vector_type(4)));
typedef float  f32x2_t  __attribute__((ext_vector_type(2)));

static __device__ __forceinline__ unsigned short f2bf(float x) {
    union { __hip_bfloat16 h; unsigned short u; } c;
    c.h = __float2bfloat16(x);   // RNE
    return c.u;
}
static __device__ __forceinline__ unsigned pk2(float lo, float hi) {
    return (unsigned)f2bf(lo) | ((unsigned)f2bf(hi) << 16);
}

// ---------------------------------------------------------------------------
// K0: W [256][256] fp32 -> bf16, swizzled Ws[kb][n][kc]  (kb=k>>5, kc=k&31)
// so GEMM B-fragment (lane: n=l&15, k=q*8+j) is one contiguous 16B load.
// ---------------------------------------------------------------------------
__global__ __launch_bounds__(256) void wconv_kernel(const float* __restrict__ W,
                                                    unsigned short* __restrict__ Ws) {
    const int kb = blockIdx.x;            // 8 blocks of 32 k-rows
    const int t  = threadIdx.x;
    __shared__ float wt[32][257];
    const int r = t >> 3, g = t & 7;
    const float* src = W + (kb * 32 + r) * F_DIM + g * 32;
#pragma unroll
    for (int i = 0; i < 8; ++i) {
        float4 v = *(const float4*)(src + i * 4);
        wt[r][g * 32 + i * 4 + 0] = v.x;
        wt[r][g * 32 + i * 4 + 1] = v.y;
        wt[r][g * 32 + i * 4 + 2] = v.z;
        wt[r][g * 32 + i * 4 + 3] = v.w;
    }
    __syncthreads();
    // thread t = output column n; write 32 bf16 (64 B) contiguous
    unsigned o[16];
#pragma unroll
    for (int k = 0; k < 32; k += 2) o[k >> 1] = pk2(wt[k][t], wt[k + 1][t]);
    uint4* dst = (uint4*)(Ws + kb * 8192 + t * 32);
#pragma unroll
    for (int i = 0; i < 4; ++i) dst[i] = make_uint4(o[4*i], o[4*i+1], o[4*i+2], o[4*i+3]);
}

// ---------------------------------------------------------------------------
// K1: per 32-row band: rowsum(A) -> d=rsqrt, dvec; X = d*H -> bf16 swizzled
// Xs[kb][n][kc].
// CAMPING FIX: A's row pitch is 32KB (pow-2). Lockstep column windows across
// rows put all concurrent traffic on the same HBM channel bits (measured
// ~1.8 TB/s). Rotate each row's sweep start by (global_row & 63) so
// concurrent windows cover the whole 32KB row. Rowsum is order-independent.
// ---------------------------------------------------------------------------
__global__ __launch_bounds__(1024) void prep_kernel(const float* __restrict__ A,
                                                    const float* __restrict__ H,
                                                    float* __restrict__ dvec,
                                                    unsigned short* __restrict__ Xs) {
    const int kb = blockIdx.x;            // 256 blocks, 32 rows each
    const int t  = threadIdx.x;
    __shared__ float psum[32][33];
    __shared__ float dl[32];
    __shared__ float ht[32][257];

    const int r = t >> 5, g = t & 31;     // 32 threads per row
    const int rot = (kb * 32 + r) & 63;   // per-row rotation of the sweep
    const float* arow = A + (size_t)(kb * 32 + r) * N_ROWS;
    float s0 = 0.f, s1 = 0.f, s2 = 0.f, s3 = 0.f;
#pragma unroll 8
    for (int i = 0; i < 64; ++i) {
        const int ii = (i + rot) & 63;
        f32x4_t v = __builtin_nontemporal_load((f32x4_t*)(arow + (ii * 32 + g) * 4));
        s0 += v.x; s1 += v.y; s2 += v.z; s3 += v.w;
    }
    psum[r][g] = (s0 + s1) + (s2 + s3);
    __syncthreads();
    if (t < 32) {
        float s = 0.f;
#pragma unroll
        for (int i = 0; i < 32; ++i) s += psum[t][i];
        float d = 1.0f / sqrtf(s);
        dl[t] = d;
        dvec[kb * 32 + t] = d;
    }
    __syncthreads();
    {   // load H band pre-scaled by d_row into LDS
        const int hr = t >> 5, hg = t & 31;
        const float* hsrc = H + (size_t)(kb * 32 + hr) * F_DIM + hg * 8;
        float4 v0 = ((const float4*)hsrc)[0];
        float4 v1 = ((const float4*)hsrc)[1];
        const float d = dl[hr];
        ht[hr][hg * 8 + 0] = v0.x * d;
        ht[hr][hg * 8 + 1] = v0.y * d;
        ht[hr][hg * 8 + 2] = v0.z * d;
        ht[hr][hg * 8 + 3] = v0.w * d;
        ht[hr][hg * 8 + 4] = v1.x * d;
        ht[hr][hg * 8 + 5] = v1.y * d;
        ht[hr][hg * 8 + 6] = v1.z * d;
        ht[hr][hg * 8 + 7] = v1.w * d;
    }
    __syncthreads();
    // transpose-read: thread -> (n = t>>2, quarter q = t&3), write 16 B
    const int n = t >> 2, q = t & 3;
    unsigned o[4];
#pragma unroll
    for (int i = 0; i < 4; ++i) {
        int k = q * 8 + i * 2;
        o[i] = pk2(ht[k][n], ht[k + 1][n]);
    }
    *(uint4*)(Xs + kb * 8192 + n * 32 + q * 8) = make_uint4(o[0], o[1], o[2], o[3]);
}

// ---------------------------------------------------------------------------
// GEMM (R1-proven LDS structure): out[32-row band, 256] = Amat(fp32->bf16) @ Bs
// Bs swizzled bf16 [k>>5][n][k&31]. BM=32, BN=256, 2 x BK=32 per iter.
// 512 thr = 8 waves (wave w: cols w*32..+31). A through tiny LDS
// (fragment-order, conflict-free); B-frags direct from L2. 1-iter reg prefetch.
// NEW: ROT rotates each block's K start (camping fix, accumulation is
// order-independent); gridDim.y=2 splits K in half -> 2 blocks/CU so one
// block's barrier drain hides under the other (partials summed in gemm2
// via SUM2).
// ---------------------------------------------------------------------------
template <int KITERS, int ASTRIDE, bool DSCALE, bool RELU, bool SUM2, bool ROT>
__global__ __launch_bounds__(512) void gemm_kernel(const float* __restrict__ Amat,
                                                   const float* __restrict__ Amat2,
                                                   const unsigned short* __restrict__ Bs,
                                                   const float* __restrict__ dvec,
                                                   float* __restrict__ out) {
    const int t    = threadIdx.x;
    const int blk  = blockIdx.x;              // 32-row M tile
    const int half = blockIdx.y;              // K-split index (0 when gridDim.y==1)
    const int w = t >> 6, l = t & 63;
    const int m = l & 15, q = l >> 4;

    // Al[sub][q*256 + mt*128 + mrow*8 + j]  (bf16), frag read = contiguous 16B
    __shared__ __align__(16) unsigned short Al[2][1024];

    const int ar = t >> 4, ac = (t & 15) * 2;         // stage row / col-pair
    const float* aptr  = Amat + (size_t)(blk * 32 + ar) * ASTRIDE + ac;
    const float* aptr2 = SUM2 ? (Amat2 + (size_t)(blk * 32 + ar) * ASTRIDE + ac) : nullptr;
    const int wr_idx = (ac >> 3) * 256 + (ar >> 4) * 128 + (ar & 15) * 8 + (ac & 7);

    const unsigned short* bptr = Bs + (w * 32 + m) * 32 + q * 8;
    // +nt*512 for next 16-col tile, +8192 per sub-step, +16384 per k-iter

    const int i0    = ROT ? (((blk * 2 + half) * 37) & (KITERS - 1)) : 0;
    const int kbase = half * KITERS;

    f32x4_t acc[2][2] = {};                   // [mtile][ntile]

    f32x2_t a_cur[2]; uint4 b_cur[2][2];
    {
        const int kk = kbase + i0;
        const float* ap = aptr + (size_t)kk * 64;
        const unsigned short* bp = bptr + (size_t)kk * 16384;
#pragma unroll
        for (int s = 0; s < 2; ++s) {
            a_cur[s] = __builtin_nontemporal_load((f32x2_t*)(ap + s * 32));
            if (SUM2) {
                f32x2_t a2 = __builtin_nontemporal_load((f32x2_t*)(aptr2 + (size_t)kk * 64 + s * 32));
                a_cur[s] += a2;
            }
            b_cur[s][0] = *(const uint4*)(bp + s * 8192);
            b_cur[s][1] = *(const uint4*)(bp + s * 8192 + 512);
        }
    }

    for (int j = 0; j < KITERS; ++j) {
        f32x2_t a_nxt[2]; uint4 b_nxt[2][2];
        if (j + 1 < KITERS) {
            const int kk = kbase + ((i0 + j + 1) & (KITERS - 1));
            const float* ap = aptr + (size_t)kk * 64;
            const unsigned short* bp = bptr + (size_t)kk * 16384;
#pragma unroll
            for (int s = 0; s < 2; ++s) {
                a_nxt[s] = __builtin_nontemporal_load((f32x2_t*)(ap + s * 32));
                if (SUM2) {
                    f32x2_t a2 = __builtin_nontemporal_load((f32x2_t*)(aptr2 + (size_t)kk * 64 + s * 32));
                    a_nxt[s] += a2;
                }
                b_nxt[s][0] = *(const uint4*)(bp + s * 8192);
                b_nxt[s][1] = *(const uint4*)(bp + s * 8192 + 512);
            }
        }
        const unsigned aw0 = pk2(a_cur[0][0], a_cur[0][1]);
        const unsigned aw1 = pk2(a_cur[1][0], a_cur[1][1]);
        __syncthreads();                       // prior frag reads done
        *(unsigned*)&Al[0][wr_idx] = aw0;
        *(unsigned*)&Al[1][wr_idx] = aw1;
        __syncthreads();                       // tiles visible
#pragma unroll
        for (int s = 0; s < 2; ++s) {
            bf16x8_t af0 = *(const bf16x8_t*)&Al[s][q * 256 + m * 8];
            bf16x8_t af1 = *(const bf16x8_t*)&Al[s][q * 256 + 128 + m * 8];
            bf16x8_t bf0 = __builtin_bit_cast(bf16x8_t, b_cur[s][0]);
            bf16x8_t bf1 = __builtin_bit_cast(bf16x8_t, b_cur[s][1]);
            acc[0][0] = __builtin_amdgcn_mfma_f32_16x16x32_bf16(af0, bf0, acc[0][0], 0, 0, 0);
            acc[0][1] = __builtin_amdgcn_mfma_f32_16x16x32_bf16(af0, bf1, acc[0][1], 0, 0, 0);
            acc[1][0] = __builtin_amdgcn_mfma_f32_16x16x32_bf16(af1, bf0, acc[1][0], 0, 0, 0);
            acc[1][1] = __builtin_amdgcn_mfma_f32_16x16x32_bf16(af1, bf1, acc[1][1], 0, 0, 0);
        }
#pragma unroll
        for (int s = 0; s < 2; ++s) {
            a_cur[s]    = a_nxt[s];
            b_cur[s][0] = b_nxt[s][0];
            b_cur[s][1] = b_nxt[s][1];
        }
    }

    // epilogue: C/D layout row=q*4+r, col=lane&15; K-split half -> own partial
    float* obase = out + (size_t)half * ((size_t)N_ROWS * F_DIM);
    const int gcol0 = w * 32 + m;
#pragma unroll
    for (int mt = 0; mt < 2; ++mt) {
#pragma unroll
        for (int r = 0; r < 4; ++r) {
            const int grow = blk * 32 + mt * 16 + q * 4 + r;
            float ds = 1.0f;
            if (DSCALE) ds = dvec[grow];
#pragma unroll
            for (int nt = 0; nt < 2; ++nt) {
                float v = acc[mt][nt][r] * ds;
                if (RELU) v = fmaxf(v, 0.f);
                obase[(size_t)grow * F_DIM + gcol0 + nt * 16] = v;
            }
        }
    }
}

// ---------------------------------------------------------------------------
extern "C" void kernel_launch(void* const* d_in, const int* in_sizes, int n_in,
                              void* d_out, int out_size, void* d_ws, size_t ws_size,
                              hipStream_t stream) {
    (void)in_sizes; (void)n_in; (void)out_size; (void)ws_size;
    const float* H = (const float*)d_in[0];
    const float* A = (const float*)d_in[1];
    const float* W = (const float*)d_in[2];
    float* out = (float*)d_out;

    char* ws = (char*)d_ws;
    float*          dvec = (float*)ws;                                     //  32 KB
    unsigned short* Xs   = (unsigned short*)(ws + (32 << 10));             //   4 MB
    unsigned short* Wsz  = (unsigned short*)(ws + (32 << 10) + (4 << 20)); // 128 KB
    float*          Y1   = (float*)(ws + (32 << 10) + (4 << 20) + (128 << 10)); // 8 MB
    float*          Y2   = Y1 + (size_t)N_ROWS * F_DIM;                    //   8 MB

    wconv_kernel<<<dim3(8),   dim3(256),  0, stream>>>(W, Wsz);
    prep_kernel <<<dim3(256), dim3(1024), 0, stream>>>(A, H, dvec, Xs);
    // gemm1: K split across gridDim.y (64 iters each), K-start rotation on.
    gemm_kernel<64, 8192, true,  false, false, true ><<<dim3(256, 2), dim3(512), 0, stream>>>(A, nullptr, Xs, dvec, Y1);
    // gemm2: sums Y1+Y2 partials on load, applies relu.
    gemm_kernel<4,   256,  false, true,  true,  false><<<dim3(256, 1), dim3(512), 0, stream>>>(Y1, Y2, Wsz, nullptr, out);
}